// Round 8
// baseline (125.685 us; speedup 1.0000x reference)
//
#include <hip/hip_runtime.h>
#include <math.h>

typedef __attribute__((ext_vector_type(8))) short short8;
typedef __attribute__((ext_vector_type(4))) float f32x4;

#define BB 8192      // batch
#define CC 1000      // classes
#define NN 9192      // B + C real columns
#define NPAD 9216    // padded
#define DD 128       // feature dim
#define RB 64        // rows per block
#define NSPLIT 6     // column splits (blockIdx.y) -> grid 768 = 3 blocks/CU exactly
#define CPW 384      // columns per wave = 9216/(NSPLIT*4)
#define NT 12        // 32-col chunks per wave
#define K2F 14.426950408889634f   // (1/T) * log2(e)

// ---- workspace layout (float offsets) ----
#define WS_BSUM  0        // [2048] per-block lp sums (corr)
#define WS_CLS   2048     // [1024] int batch histogram
#define WS_OFF   3072     // [1024] int CSR offsets
#define WS_LIST  4096     // [9216] int CSR column lists
#define WS_RCP0  13312    // [9216] 1/cnt
#define WS_RCPD  22528    // [9216] 1/(cnt-1) - 1/cnt
#define WS_SPART 32768    // [6*8192]
#define WS_F2    98304    // fragment-major bf16 [9216*128]

static __device__ __forceinline__ unsigned short f2bf(float x) {
    unsigned int b = __float_as_uint(x);
    unsigned int r = (b + 0x7FFFu + ((b >> 16) & 1u)) >> 16;   // RNE
    return (unsigned short)r;
}
static __device__ __forceinline__ float fexp2(float x) {
    float r; asm("v_exp_f32 %0, %1" : "=v"(r) : "v"(x)); return r;
}
static __device__ __forceinline__ float flog2(float x) {
    float r; asm("v_log_f32 %0, %1" : "=v"(r) : "v"(x)); return r;
}
// element (row j, dim k) of fragment-major F2
static __device__ __forceinline__ float f2elem(const unsigned short* __restrict__ F2,
                                               int j, int k) {
    int u = ((j >> 4) * 4 + (k >> 5)) * 64 + ((k >> 3) & 3) * 16 + (j & 15);
    return __uint_as_float((unsigned int)F2[u * 8 + (k & 7)] << 16);
}

// ---- one block, 1024 threads: hist + rcp tables + CSR (scan, fill, sort) ----
__global__ __launch_bounds__(1024) void setup_kernel(
    const int* __restrict__ tgt, int* __restrict__ cls, int* __restrict__ off,
    int* __restrict__ list, float* __restrict__ rcp0, float* __restrict__ rcpd)
{
    __shared__ int h[1024];
    __shared__ int s[1024];
    __shared__ int cur[1024];
    const int tid = threadIdx.x;

    h[tid] = 0;
    __syncthreads();
    for (int i = tid; i < BB; i += 1024) atomicAdd(&h[tgt[i]], 1);
    __syncthreads();

    const int cnt_b = h[tid];            // batch members of class tid
    cls[tid] = cnt_b;

    // per-column weights
    for (int j = tid; j < NPAD; j += 1024) {
        if (j < NN) {
            int c = (j < BB) ? tgt[j] : (j - BB);
            int cnt = h[c] + 1;          // +1: the class center itself
            float a = 1.0f / (float)cnt;
            rcp0[j] = a;
            rcpd[j] = ((cnt > 1) ? 1.0f / (float)(cnt - 1) : 0.0f) - a;
        } else { rcp0[j] = 0.0f; rcpd[j] = 0.0f; }
    }

    // exclusive scan of segment lengths (members + center)
    int v = (tid < CC) ? cnt_b + 1 : 0;
    s[tid] = v;
    __syncthreads();
    for (int d = 1; d < 1024; d <<= 1) {
        int t = (tid >= d) ? s[tid - d] : 0;
        __syncthreads();
        s[tid] += t;
        __syncthreads();
    }
    const int o = s[tid] - v;
    if (tid < CC) { off[tid] = o; cur[tid] = o; }
    __syncthreads();

    // fill CSR lists (LDS atomic cursors)
    for (int j = tid; j < NN; j += 1024) {
        int c = (j < BB) ? tgt[j] : (j - BB);
        int r = atomicAdd(&cur[c], 1);
        list[r] = j;
    }
    __syncthreads();

    // deterministic order within each segment
    if (tid < CC) {
        int n = cnt_b + 1;
        for (int a = 1; a < n; ++a) {
            int key = list[o + a]; int b = a - 1;
            while (b >= 0 && list[o + b] > key) { list[o + b + 1] = list[o + b]; --b; }
            list[o + b + 1] = key;
        }
    }
}

// F2 fragment-major: 16B unit u = (j16*4 + ks)*64 + l4*16 + l15 holds
// (col j = j16*16+l15, k = ks*32 + l4*8 .. +8) as 8 bf16.
__global__ void cvt_kernel(const float* __restrict__ feats, const float* __restrict__ ctrs,
                           unsigned short* __restrict__ F2) {
    int u = blockIdx.x * 256 + threadIdx.x;       // one per 8 elements
    if (u >= NPAD * 16) return;
    int j = u >> 4, quad = u & 15;
    int k0 = quad * 8;
    float4 v0 = {0.f,0.f,0.f,0.f}, v1 = {0.f,0.f,0.f,0.f};
    if (j < BB) {
        v0 = *(const float4*)&feats[(size_t)j * DD + k0];
        v1 = *(const float4*)&feats[(size_t)j * DD + k0 + 4];
    } else if (j < NN) {
        v0 = *(const float4*)&ctrs[(size_t)(j - BB) * DD + k0];
        v1 = *(const float4*)&ctrs[(size_t)(j - BB) * DD + k0 + 4];
    }
    short8 o;
    o[0]=f2bf(v0.x); o[1]=f2bf(v0.y); o[2]=f2bf(v0.z); o[3]=f2bf(v0.w);
    o[4]=f2bf(v1.x); o[5]=f2bf(v1.y); o[6]=f2bf(v1.z); o[7]=f2bf(v1.w);
    size_t offb = (size_t)((((j >> 4) * 4 + (quad >> 2)) * 64 + (quad & 3) * 16 + (j & 15)) * 8);
    *(short8*)&F2[offb] = o;
}

static __device__ __forceinline__ void loadB(const unsigned short* __restrict__ F2,
                                             int j0, int lane8, short8 (&buf)[8]) {
#pragma unroll
    for (int fn = 0; fn < 2; ++fn)
#pragma unroll
        for (int ks = 0; ks < 4; ++ks)
            buf[fn * 4 + ks] = *(const short8*)&F2[(size_t)((((j0 >> 4) + fn) * 4 + ks) * 512 + lane8)];
}

static __device__ __forceinline__ void mfma_chunk(const short8 (&af)[4][4], const short8 (&b)[8],
                                                  f32x4 (&acc)[4][2]) {
    const f32x4 z4 = {0.f, 0.f, 0.f, 0.f};
#pragma unroll
    for (int fm = 0; fm < 4; ++fm)
#pragma unroll
        for (int fn = 0; fn < 2; ++fn)
            acc[fm][fn] = __builtin_amdgcn_mfma_f32_16x16x32_bf16(af[0][fm], b[fn * 4], z4, 0, 0, 0);
#pragma unroll
    for (int ks = 1; ks < 4; ++ks)
#pragma unroll
        for (int fm = 0; fm < 4; ++fm)
#pragma unroll
            for (int fn = 0; fn < 2; ++fn)
                acc[fm][fn] = __builtin_amdgcn_mfma_f32_16x16x32_bf16(
                    af[ks][fm], b[fn * 4 + ks], acc[fm][fn], 0, 0, 0);
}

// 3 VALU per element: fma -> v_exp -> fmac  (no masks, no metadata)
static __device__ __forceinline__ void epi(const f32x4 (&acc)[4][2], const float (&r0)[2],
                                           float (&Sl)[16]) {
#pragma unroll
    for (int fm = 0; fm < 4; ++fm)
#pragma unroll
        for (int q = 0; q < 4; ++q) {
            float s = Sl[fm * 4 + q];
#pragma unroll
            for (int fn = 0; fn < 2; ++fn) {
                float l2 = fmaf(acc[fm][fn][q], K2F, -K2F);
                s = fmaf(fexp2(l2), r0[fn], s);
            }
            Sl[fm * 4 + q] = s;
        }
}

__global__ __launch_bounds__(256, 3) void main_kernel(
    const unsigned short* __restrict__ F2, const float* __restrict__ rcp0,
    float* __restrict__ S_part)
{
    __shared__ float combS[3][64];

    const int tid  = threadIdx.x;
    const int lane = tid & 63;
    const int wave = tid >> 6;
    const int l15 = lane & 15, l4 = lane >> 4;
    const int lane8 = lane * 8;
    const int row0 = blockIdx.x * RB;
    const int split = blockIdx.y;
    const int cb = (split * 4 + wave) * CPW;     // this wave's column base

    // A fragments straight from global (rows row0..row0+63), persistent
    short8 af[4][4];                             // [ks][fm]
#pragma unroll
    for (int fm = 0; fm < 4; ++fm)
#pragma unroll
        for (int ks = 0; ks < 4; ++ks)
            af[ks][fm] = *(const short8*)&F2[(size_t)((((row0 >> 4) + fm) * 4 + ks) * 512 + lane8)];

    float Sl[16];
#pragma unroll
    for (int x = 0; x < 16; ++x) Sl[x] = 0.f;

    short8 b[8];
    float r0A[2], r0B[2];
    loadB(F2, cb, lane8, b);
    r0A[0] = rcp0[cb + l15]; r0A[1] = rcp0[cb + 16 + l15];

#pragma unroll 1
    for (int tt = 0; tt < NT; tt += 2) {
        {   // even chunk tt (uses r0A)
            f32x4 acc[4][2];
            mfma_chunk(af, b, acc);              // consumes b
            {
                int jn = cb + (tt + 1) * 32;
                loadB(F2, jn, lane8, b);
                r0B[0] = rcp0[jn + l15]; r0B[1] = rcp0[jn + 16 + l15];
            }
            epi(acc, r0A, Sl);                   // hides next-chunk load latency
        }
        {   // odd chunk tt+1 (uses r0B)
            f32x4 acc[4][2];
            mfma_chunk(af, b, acc);
            if (tt + 2 < NT) {
                int jn = cb + (tt + 2) * 32;
                loadB(F2, jn, lane8, b);
                r0A[0] = rcp0[jn + l15]; r0A[1] = rcp0[jn + 16 + l15];
            }
            epi(acc, r0B, Sl);
        }
    }

    // 16-lane column reduce (tree), then cross-wave combine via tiny LDS
#pragma unroll
    for (int idx = 0; idx < 16; ++idx) {
        float S = Sl[idx];
#pragma unroll
        for (int off = 1; off < 16; off <<= 1) S += __shfl_xor(S, off, 64);
        Sl[idx] = S;
        if (wave > 0 && l15 == 0) {
            int rl = (idx >> 2) * 16 + l4 * 4 + (idx & 3);
            combS[wave - 1][rl] = S;
        }
    }
    __syncthreads();
    if (wave == 0 && l15 == 0) {
#pragma unroll
        for (int idx = 0; idx < 16; ++idx) {
            int rl = (idx >> 2) * 16 + l4 * 4 + (idx & 3);
            S_part[split * BB + row0 + rl] = Sl[idx] + combS[0][rl] + combS[1][rl] + combS[2][rl];
        }
    }
}

// one wave per row: sparse mask correction + P + final lp, block partial sum
__global__ __launch_bounds__(256) void corr_kernel(
    const unsigned short* __restrict__ F2, const int* __restrict__ tgt,
    const int* __restrict__ cls, const int* __restrict__ off,
    const int* __restrict__ list, const float* __restrict__ rcp0,
    const float* __restrict__ rcpd, const float* __restrict__ S_part,
    float* __restrict__ bsum)
{
    __shared__ float wred[4];
    const int wave = threadIdx.x >> 6, lane = threadIdx.x & 63;
    const int i = blockIdx.x * 4 + wave;
    const int c = tgt[i];
    const int n = cls[c];                         // = npos (>=1: row i itself)
    const int o = off[c];
    const int k0 = lane * 2;
    const float fa = f2elem(F2, i, k0), fb = f2elem(F2, i, k0 + 1);

    float CorrS = 0.f, P = 0.f;
    for (int idx = 0; idx <= n; ++idx) {          // n batch members + 1 center
        int j = list[o + idx];
        float d = fa * f2elem(F2, j, k0) + fb * f2elem(F2, j, k0 + 1);
#pragma unroll
        for (int s = 1; s < 64; s <<= 1) d += __shfl_xor(d, s, 64);
        float e = fexp2(fmaf(d, K2F, -K2F));
        if (j == i) CorrS -= e * rcp0[i];         // remove self from S0
        else        { CorrS += e * rcpd[j]; P += d; }
    }
    float S = CorrS;
#pragma unroll
    for (int s = 0; s < NSPLIT; ++s) S += S_part[s * BB + i];
    float lp = fmaf(K2F, P / (float)n, -K2F) - flog2(S);   // log2 units

    if (lane == 0) wred[wave] = lp;
    __syncthreads();
    if (threadIdx.x == 0) bsum[blockIdx.x] = wred[0] + wred[1] + wred[2] + wred[3];
}

__global__ void out_kernel(const float* __restrict__ bsum, float* __restrict__ out) {
    const int tid = threadIdx.x;                  // 1024 threads
    float v = bsum[tid] + bsum[tid + 1024];
#pragma unroll
    for (int off = 1; off < 64; off <<= 1) v += __shfl_xor(v, off, 64);
    __shared__ float wsum[16];
    if ((tid & 63) == 0) wsum[tid >> 6] = v;
    __syncthreads();
    if (tid == 0) {
        float t = 0.f;
#pragma unroll
        for (int w = 0; w < 16; ++w) t += wsum[w];
        out[0] = -0.6931471805599453f * (t / (float)BB);   // ln2 * mean, negated
    }
}

extern "C" void kernel_launch(void* const* d_in, const int* in_sizes, int n_in,
                              void* d_out, int out_size, void* d_ws, size_t ws_size,
                              hipStream_t stream) {
    const float* ctrs  = (const float*)d_in[0];   // centers1 [1000,128]
    const float* feats = (const float*)d_in[1];   // features [8192,128]
    const int*   tgt   = (const int*)d_in[2];     // targets  [8192] int32
    float* out = (float*)d_out;
    float* ws  = (float*)d_ws;

    float* bsum = ws + WS_BSUM;
    int*   cls  = (int*)(ws + WS_CLS);
    int*   off  = (int*)(ws + WS_OFF);
    int*   list = (int*)(ws + WS_LIST);
    float* rcp0 = ws + WS_RCP0;
    float* rcpd = ws + WS_RCPD;
    float* Sp   = ws + WS_SPART;
    unsigned short* F2 = (unsigned short*)(ws + WS_F2);

    setup_kernel<<<dim3(1), dim3(1024), 0, stream>>>(tgt, cls, off, list, rcp0, rcpd);
    cvt_kernel<<<dim3(NPAD * 16 / 256), dim3(256), 0, stream>>>(feats, ctrs, F2);
    main_kernel<<<dim3(BB / RB, NSPLIT), dim3(256), 0, stream>>>(F2, rcp0, Sp);
    corr_kernel<<<dim3(BB / 4), dim3(256), 0, stream>>>(F2, tgt, cls, off, list, rcp0, rcpd, Sp, bsum);
    out_kernel<<<dim3(1), dim3(1024), 0, stream>>>(bsum, out);
}

// Round 9
// 86.202 us; speedup vs baseline: 1.4580x; 1.4580x over previous
//
#include <hip/hip_runtime.h>
#include <math.h>

typedef __attribute__((ext_vector_type(8))) short short8;
typedef __attribute__((ext_vector_type(4))) float f32x4;

#define BB 8192      // batch
#define CC 1000      // classes
#define NN 9192      // B + C real columns
#define NPAD 9216    // padded
#define DD 128       // feature dim
#define RB 64        // rows per block
#define NSPLIT 6     // column splits (blockIdx.y) -> grid 768 = 3 blocks/CU exactly
#define CPW 384      // columns per wave = 9216/(NSPLIT*4)
#define NT 24        // 16-col chunks per wave
#define K2F 14.426950408889634f   // (1/T) * log2(e)

// ---- workspace layout (float offsets) ----
#define WS_BSUM  0        // [2048] per-block lp sums (corr)
#define WS_CLS   2048     // [1024] int batch histogram
#define WS_OFF   3072     // [1024] int CSR offsets
#define WS_LIST  4096     // [9216] int CSR column lists
#define WS_RCP0  13312    // [9216] 1/cnt
#define WS_RCPD  22528    // [9216] 1/(cnt-1) - 1/cnt
#define WS_SPART 32768    // [6*8192]
#define WS_F2    98304    // fragment-major bf16 [9216*128]

static __device__ __forceinline__ unsigned short f2bf(float x) {
    unsigned int b = __float_as_uint(x);
    unsigned int r = (b + 0x7FFFu + ((b >> 16) & 1u)) >> 16;   // RNE
    return (unsigned short)r;
}
static __device__ __forceinline__ float fexp2(float x) {
    float r; asm("v_exp_f32 %0, %1" : "=v"(r) : "v"(x)); return r;
}
static __device__ __forceinline__ float flog2(float x) {
    float r; asm("v_log_f32 %0, %1" : "=v"(r) : "v"(x)); return r;
}
// element (row j, dim k) of fragment-major F2
static __device__ __forceinline__ float f2elem(const unsigned short* __restrict__ F2,
                                               int j, int k) {
    int u = ((j >> 4) * 4 + (k >> 5)) * 64 + ((k >> 3) & 3) * 16 + (j & 15);
    return __uint_as_float((unsigned int)F2[u * 8 + (k & 7)] << 16);
}

// ---- one block, 1024 threads: hist + rcp tables + CSR (scan, fill, sort) ----
__global__ __launch_bounds__(1024) void setup_kernel(
    const int* __restrict__ tgt, int* __restrict__ cls, int* __restrict__ off,
    int* __restrict__ list, float* __restrict__ rcp0, float* __restrict__ rcpd)
{
    __shared__ int h[1024];
    __shared__ int s[1024];
    __shared__ int cur[1024];
    const int tid = threadIdx.x;

    h[tid] = 0;
    __syncthreads();
    for (int i = tid; i < BB; i += 1024) atomicAdd(&h[tgt[i]], 1);
    __syncthreads();

    const int cnt_b = h[tid];            // batch members of class tid
    cls[tid] = cnt_b;

    // per-column weights
    for (int j = tid; j < NPAD; j += 1024) {
        if (j < NN) {
            int c = (j < BB) ? tgt[j] : (j - BB);
            int cnt = h[c] + 1;          // +1: the class center itself
            float a = 1.0f / (float)cnt;
            rcp0[j] = a;
            rcpd[j] = ((cnt > 1) ? 1.0f / (float)(cnt - 1) : 0.0f) - a;
        } else { rcp0[j] = 0.0f; rcpd[j] = 0.0f; }
    }

    // exclusive scan of segment lengths (members + center)
    int v = (tid < CC) ? cnt_b + 1 : 0;
    s[tid] = v;
    __syncthreads();
    for (int d = 1; d < 1024; d <<= 1) {
        int t = (tid >= d) ? s[tid - d] : 0;
        __syncthreads();
        s[tid] += t;
        __syncthreads();
    }
    const int o = s[tid] - v;
    if (tid < CC) { off[tid] = o; cur[tid] = o; }
    __syncthreads();

    // fill CSR lists (LDS atomic cursors)
    for (int j = tid; j < NN; j += 1024) {
        int c = (j < BB) ? tgt[j] : (j - BB);
        int r = atomicAdd(&cur[c], 1);
        list[r] = j;
    }
    __syncthreads();

    // deterministic order within each segment
    if (tid < CC) {
        int n = cnt_b + 1;
        for (int a = 1; a < n; ++a) {
            int key = list[o + a]; int b = a - 1;
            while (b >= 0 && list[o + b] > key) { list[o + b + 1] = list[o + b]; --b; }
            list[o + b + 1] = key;
        }
    }
}

// F2 fragment-major: 16B unit u = (j16*4 + ks)*64 + l4*16 + l15 holds
// (col j = j16*16+l15, k = ks*32 + l4*8 .. +8) as 8 bf16.
__global__ void cvt_kernel(const float* __restrict__ feats, const float* __restrict__ ctrs,
                           unsigned short* __restrict__ F2) {
    int u = blockIdx.x * 256 + threadIdx.x;       // one per 8 elements
    if (u >= NPAD * 16) return;
    int j = u >> 4, quad = u & 15;
    int k0 = quad * 8;
    float4 v0 = {0.f,0.f,0.f,0.f}, v1 = {0.f,0.f,0.f,0.f};
    if (j < BB) {
        v0 = *(const float4*)&feats[(size_t)j * DD + k0];
        v1 = *(const float4*)&feats[(size_t)j * DD + k0 + 4];
    } else if (j < NN) {
        v0 = *(const float4*)&ctrs[(size_t)(j - BB) * DD + k0];
        v1 = *(const float4*)&ctrs[(size_t)(j - BB) * DD + k0 + 4];
    }
    short8 o;
    o[0]=f2bf(v0.x); o[1]=f2bf(v0.y); o[2]=f2bf(v0.z); o[3]=f2bf(v0.w);
    o[4]=f2bf(v1.x); o[5]=f2bf(v1.y); o[6]=f2bf(v1.z); o[7]=f2bf(v1.w);
    size_t offb = (size_t)((((j >> 4) * 4 + (quad >> 2)) * 64 + (quad & 3) * 16 + (j & 15)) * 8);
    *(short8*)&F2[offb] = o;
}

// one 16-col x 32-k fragment group (4 x 1KB coalesced loads)
static __device__ __forceinline__ void loadB(const unsigned short* __restrict__ F2,
                                             int j0, int lane8, short8 (&buf)[4]) {
#pragma unroll
    for (int ks = 0; ks < 4; ++ks)
        buf[ks] = *(const short8*)&F2[(size_t)(((j0 >> 4) * 4 + ks) * 512 + lane8)];
}

// 16 MFMAs: 64 rows x 16 cols x full K=128
static __device__ __forceinline__ void mfma16(const short8 (&af)[4][4], const short8 (&b)[4],
                                              f32x4 (&acc)[4]) {
    const f32x4 z4 = {0.f, 0.f, 0.f, 0.f};
#pragma unroll
    for (int fm = 0; fm < 4; ++fm)
        acc[fm] = __builtin_amdgcn_mfma_f32_16x16x32_bf16(af[0][fm], b[0], z4, 0, 0, 0);
#pragma unroll
    for (int ks = 1; ks < 4; ++ks)
#pragma unroll
        for (int fm = 0; fm < 4; ++fm)
            acc[fm] = __builtin_amdgcn_mfma_f32_16x16x32_bf16(
                af[ks][fm], b[ks], acc[fm], 0, 0, 0);
}

// 3 VALU per element: fma -> v_exp -> fmac  (no masks, no metadata)
static __device__ __forceinline__ void epi16(const f32x4 (&acc)[4], float r0, float (&Sl)[16]) {
#pragma unroll
    for (int fm = 0; fm < 4; ++fm)
#pragma unroll
        for (int q = 0; q < 4; ++q) {
            float l2 = fmaf(acc[fm][q], K2F, -K2F);
            Sl[fm * 4 + q] = fmaf(fexp2(l2), r0, Sl[fm * 4 + q]);
        }
}

__global__ __launch_bounds__(256, 3) void main_kernel(
    const unsigned short* __restrict__ F2, const float* __restrict__ rcp0,
    float* __restrict__ S_part)
{
    __shared__ float combS[3][64];

    const int tid  = threadIdx.x;
    const int lane = tid & 63;
    const int wave = tid >> 6;
    const int l15 = lane & 15, l4 = lane >> 4;
    const int lane8 = lane * 8;
    const int row0 = blockIdx.x * RB;
    const int split = blockIdx.y;
    const int cb = (split * 4 + wave) * CPW;     // this wave's column base

    // A fragments straight from global (rows row0..row0+63), persistent
    short8 af[4][4];                             // [ks][fm]
#pragma unroll
    for (int fm = 0; fm < 4; ++fm)
#pragma unroll
        for (int ks = 0; ks < 4; ++ks)
            af[ks][fm] = *(const short8*)&F2[(size_t)((((row0 >> 4) + fm) * 4 + ks) * 512 + lane8)];

    float Sl[16];
#pragma unroll
    for (int x = 0; x < 16; ++x) Sl[x] = 0.f;

    short8 bA[4], bB[4];
    float r0A, r0B;
    loadB(F2, cb, lane8, bA);
    r0A = rcp0[cb + l15];

#pragma unroll 1
    for (int tt = 0; tt < NT; tt += 2) {
        {   // prefetch odd chunk, compute even chunk
            const int j1 = cb + (tt + 1) * 16;
            loadB(F2, j1, lane8, bB);
            r0B = rcp0[j1 + l15];
            f32x4 acc[4];
            mfma16(af, bA, acc);
            epi16(acc, r0A, Sl);
        }
        {   // prefetch next even chunk, compute odd chunk
            if (tt + 2 < NT) {
                const int j2 = cb + (tt + 2) * 16;
                loadB(F2, j2, lane8, bA);
                r0A = rcp0[j2 + l15];
            }
            f32x4 acc[4];
            mfma16(af, bB, acc);
            epi16(acc, r0B, Sl);
        }
    }

    // 16-lane column reduce (tree), then cross-wave combine via tiny LDS
#pragma unroll
    for (int idx = 0; idx < 16; ++idx) {
        float S = Sl[idx];
#pragma unroll
        for (int off = 1; off < 16; off <<= 1) S += __shfl_xor(S, off, 64);
        Sl[idx] = S;
        if (wave > 0 && l15 == 0) {
            int rl = (idx >> 2) * 16 + l4 * 4 + (idx & 3);
            combS[wave - 1][rl] = S;
        }
    }
    __syncthreads();
    if (wave == 0 && l15 == 0) {
#pragma unroll
        for (int idx = 0; idx < 16; ++idx) {
            int rl = (idx >> 2) * 16 + l4 * 4 + (idx & 3);
            S_part[split * BB + row0 + rl] = Sl[idx] + combS[0][rl] + combS[1][rl] + combS[2][rl];
        }
    }
}

// one wave per row: sparse mask correction + P + final lp, block partial sum
__global__ __launch_bounds__(256) void corr_kernel(
    const unsigned short* __restrict__ F2, const int* __restrict__ tgt,
    const int* __restrict__ cls, const int* __restrict__ off,
    const int* __restrict__ list, const float* __restrict__ rcp0,
    const float* __restrict__ rcpd, const float* __restrict__ S_part,
    float* __restrict__ bsum)
{
    __shared__ float wred[4];
    const int wave = threadIdx.x >> 6, lane = threadIdx.x & 63;
    const int i = blockIdx.x * 4 + wave;
    const int c = tgt[i];
    const int n = cls[c];                         // = npos (>=1: row i itself)
    const int o = off[c];
    const int k0 = lane * 2;
    const float fa = f2elem(F2, i, k0), fb = f2elem(F2, i, k0 + 1);

    float CorrS = 0.f, P = 0.f;
    for (int idx = 0; idx <= n; ++idx) {          // n batch members + 1 center
        int j = list[o + idx];
        float d = fa * f2elem(F2, j, k0) + fb * f2elem(F2, j, k0 + 1);
#pragma unroll
        for (int s = 1; s < 64; s <<= 1) d += __shfl_xor(d, s, 64);
        float e = fexp2(fmaf(d, K2F, -K2F));
        if (j == i) CorrS -= e * rcp0[i];         // remove self from S0
        else        { CorrS += e * rcpd[j]; P += d; }
    }
    float S = CorrS;
#pragma unroll
    for (int s = 0; s < NSPLIT; ++s) S += S_part[s * BB + i];
    float lp = fmaf(K2F, P / (float)n, -K2F) - flog2(S);   // log2 units

    if (lane == 0) wred[wave] = lp;
    __syncthreads();
    if (threadIdx.x == 0) bsum[blockIdx.x] = wred[0] + wred[1] + wred[2] + wred[3];
}

__global__ void out_kernel(const float* __restrict__ bsum, float* __restrict__ out) {
    const int tid = threadIdx.x;                  // 1024 threads
    float v = bsum[tid] + bsum[tid + 1024];
#pragma unroll
    for (int off = 1; off < 64; off <<= 1) v += __shfl_xor(v, off, 64);
    __shared__ float wsum[16];
    if ((tid & 63) == 0) wsum[tid >> 6] = v;
    __syncthreads();
    if (tid == 0) {
        float t = 0.f;
#pragma unroll
        for (int w = 0; w < 16; ++w) t += wsum[w];
        out[0] = -0.6931471805599453f * (t / (float)BB);   // ln2 * mean, negated
    }
}

extern "C" void kernel_launch(void* const* d_in, const int* in_sizes, int n_in,
                              void* d_out, int out_size, void* d_ws, size_t ws_size,
                              hipStream_t stream) {
    const float* ctrs  = (const float*)d_in[0];   // centers1 [1000,128]
    const float* feats = (const float*)d_in[1];   // features [8192,128]
    const int*   tgt   = (const int*)d_in[2];     // targets  [8192] int32
    float* out = (float*)d_out;
    float* ws  = (float*)d_ws;

    float* bsum = ws + WS_BSUM;
    int*   cls  = (int*)(ws + WS_CLS);
    int*   off  = (int*)(ws + WS_OFF);
    int*   list = (int*)(ws + WS_LIST);
    float* rcp0 = ws + WS_RCP0;
    float* rcpd = ws + WS_RCPD;
    float* Sp   = ws + WS_SPART;
    unsigned short* F2 = (unsigned short*)(ws + WS_F2);

    setup_kernel<<<dim3(1), dim3(1024), 0, stream>>>(tgt, cls, off, list, rcp0, rcpd);
    cvt_kernel<<<dim3(NPAD * 16 / 256), dim3(256), 0, stream>>>(feats, ctrs, F2);
    main_kernel<<<dim3(BB / RB, NSPLIT), dim3(256), 0, stream>>>(F2, rcp0, Sp);
    corr_kernel<<<dim3(BB / 4), dim3(256), 0, stream>>>(F2, tgt, cls, off, list, rcp0, rcpd, Sp, bsum);
    out_kernel<<<dim3(1), dim3(1024), 0, stream>>>(bsum, out);
}

// Round 10
// 82.694 us; speedup vs baseline: 1.5199x; 1.0424x over previous
//
#include <hip/hip_runtime.h>
#include <math.h>

typedef __attribute__((ext_vector_type(8))) short short8;
typedef __attribute__((ext_vector_type(4))) float f32x4;

#define BB 8192      // batch
#define CC 1000      // classes
#define NN 9192      // B + C real columns
#define NPAD 9216    // padded
#define DD 128       // feature dim
#define RB 64        // rows per block
#define NSPLIT 4     // column splits (blockIdx.y) -> grid 512 = 2 blocks/CU exactly
#define CPW 576      // columns per wave = 9216/(NSPLIT*4)
#define NT 36        // 16-col chunks per wave (divisible by 3 for 3-buffer rotation)
#define K2F 14.426950408889634f   // (1/T) * log2(e)

// ---- workspace layout (float offsets) ----
#define WS_BSUM  0        // [2048] per-block lp sums (corr)
#define WS_CLS   2048     // [1024] int batch histogram
#define WS_OFF   3072     // [1024] int CSR offsets
#define WS_LIST  4096     // [9216] int CSR column lists
#define WS_RCP0  13312    // [9216] 1/cnt
#define WS_RCPD  22528    // [9216] 1/(cnt-1) - 1/cnt
#define WS_SPART 32768    // [4*8192]
#define WS_F2    98304    // fragment-major bf16 [9216*128]

static __device__ __forceinline__ unsigned short f2bf(float x) {
    unsigned int b = __float_as_uint(x);
    unsigned int r = (b + 0x7FFFu + ((b >> 16) & 1u)) >> 16;   // RNE
    return (unsigned short)r;
}
static __device__ __forceinline__ float fexp2(float x) {
    float r; asm("v_exp_f32 %0, %1" : "=v"(r) : "v"(x)); return r;
}
static __device__ __forceinline__ float flog2(float x) {
    float r; asm("v_log_f32 %0, %1" : "=v"(r) : "v"(x)); return r;
}
// element (row j, dim k) of fragment-major F2
static __device__ __forceinline__ float f2elem(const unsigned short* __restrict__ F2,
                                               int j, int k) {
    int u = ((j >> 4) * 4 + (k >> 5)) * 64 + ((k >> 3) & 3) * 16 + (j & 15);
    return __uint_as_float((unsigned int)F2[u * 8 + (k & 7)] << 16);
}

// ---- fused prep: blocks 0..143 convert fp32 -> fragment-major bf16;
//      block 144 builds hist + rcp tables + CSR (scan, fill, sort) ----
__global__ __launch_bounds__(1024) void prep_kernel(
    const float* __restrict__ feats, const float* __restrict__ ctrs,
    const int* __restrict__ tgt, unsigned short* __restrict__ F2,
    int* __restrict__ cls, int* __restrict__ off, int* __restrict__ list,
    float* __restrict__ rcp0, float* __restrict__ rcpd)
{
    const int tid = threadIdx.x;
    if (blockIdx.x < 144) {
        // cvt: one short8-unit per thread.  F2 fragment-major: 16B unit
        // u = (j16*4 + ks)*64 + l4*16 + l15 holds (col j=j16*16+l15, k=ks*32+l4*8..+8)
        int u = blockIdx.x * 1024 + tid;          // < 147456 = NPAD*16
        int j = u >> 4, quad = u & 15;
        int k0 = quad * 8;
        float4 v0 = {0.f,0.f,0.f,0.f}, v1 = {0.f,0.f,0.f,0.f};
        if (j < BB) {
            v0 = *(const float4*)&feats[(size_t)j * DD + k0];
            v1 = *(const float4*)&feats[(size_t)j * DD + k0 + 4];
        } else if (j < NN) {
            v0 = *(const float4*)&ctrs[(size_t)(j - BB) * DD + k0];
            v1 = *(const float4*)&ctrs[(size_t)(j - BB) * DD + k0 + 4];
        }
        short8 o;
        o[0]=f2bf(v0.x); o[1]=f2bf(v0.y); o[2]=f2bf(v0.z); o[3]=f2bf(v0.w);
        o[4]=f2bf(v1.x); o[5]=f2bf(v1.y); o[6]=f2bf(v1.z); o[7]=f2bf(v1.w);
        size_t offb = (size_t)((((j >> 4) * 4 + (quad >> 2)) * 64 + (quad & 3) * 16 + (j & 15)) * 8);
        *(short8*)&F2[offb] = o;
        return;
    }

    // ---- setup block ----
    __shared__ int h[1024];
    __shared__ int s[1024];
    __shared__ int cur[1024];

    h[tid] = 0;
    __syncthreads();
    for (int i = tid; i < BB; i += 1024) atomicAdd(&h[tgt[i]], 1);
    __syncthreads();

    const int cnt_b = h[tid];            // batch members of class tid
    cls[tid] = cnt_b;

    // per-column weights
    for (int j = tid; j < NPAD; j += 1024) {
        if (j < NN) {
            int c = (j < BB) ? tgt[j] : (j - BB);
            int cnt = h[c] + 1;          // +1: the class center itself
            float a = 1.0f / (float)cnt;
            rcp0[j] = a;
            rcpd[j] = ((cnt > 1) ? 1.0f / (float)(cnt - 1) : 0.0f) - a;
        } else { rcp0[j] = 0.0f; rcpd[j] = 0.0f; }
    }

    // exclusive scan of segment lengths (members + center)
    int v = (tid < CC) ? cnt_b + 1 : 0;
    s[tid] = v;
    __syncthreads();
    for (int d = 1; d < 1024; d <<= 1) {
        int t = (tid >= d) ? s[tid - d] : 0;
        __syncthreads();
        s[tid] += t;
        __syncthreads();
    }
    const int o = s[tid] - v;
    if (tid < CC) { off[tid] = o; cur[tid] = o; }
    __syncthreads();

    // fill CSR lists (LDS atomic cursors)
    for (int j = tid; j < NN; j += 1024) {
        int c = (j < BB) ? tgt[j] : (j - BB);
        int r = atomicAdd(&cur[c], 1);
        list[r] = j;
    }
    __syncthreads();

    // deterministic order within each segment
    if (tid < CC) {
        int n = cnt_b + 1;
        for (int a = 1; a < n; ++a) {
            int key = list[o + a]; int b = a - 1;
            while (b >= 0 && list[o + b] > key) { list[o + b + 1] = list[o + b]; --b; }
            list[o + b + 1] = key;
        }
    }
}

// one 16-col x 32-k fragment group (4 x 1KB coalesced loads)
static __device__ __forceinline__ void loadB(const unsigned short* __restrict__ F2,
                                             int j0, int lane8, short8 (&buf)[4]) {
#pragma unroll
    for (int ks = 0; ks < 4; ++ks)
        buf[ks] = *(const short8*)&F2[(size_t)(((j0 >> 4) * 4 + ks) * 512 + lane8)];
}

// 16 MFMAs: 64 rows x 16 cols x full K=128
static __device__ __forceinline__ void mfma16(const short8 (&af)[4][4], const short8 (&b)[4],
                                              f32x4 (&acc)[4]) {
    const f32x4 z4 = {0.f, 0.f, 0.f, 0.f};
#pragma unroll
    for (int fm = 0; fm < 4; ++fm)
        acc[fm] = __builtin_amdgcn_mfma_f32_16x16x32_bf16(af[0][fm], b[0], z4, 0, 0, 0);
#pragma unroll
    for (int ks = 1; ks < 4; ++ks)
#pragma unroll
        for (int fm = 0; fm < 4; ++fm)
            acc[fm] = __builtin_amdgcn_mfma_f32_16x16x32_bf16(
                af[ks][fm], b[ks], acc[fm], 0, 0, 0);
}

// 3 VALU per element: fma -> v_exp -> fmac  (no masks, no metadata)
static __device__ __forceinline__ void epi16(const f32x4 (&acc)[4], float r0, float (&Sl)[16]) {
#pragma unroll
    for (int fm = 0; fm < 4; ++fm)
#pragma unroll
        for (int q = 0; q < 4; ++q) {
            float l2 = fmaf(acc[fm][q], K2F, -K2F);
            Sl[fm * 4 + q] = fmaf(fexp2(l2), r0, Sl[fm * 4 + q]);
        }
}

__global__ __launch_bounds__(256, 2) void main_kernel(
    const unsigned short* __restrict__ F2, const float* __restrict__ rcp0,
    float* __restrict__ S_part)
{
    __shared__ float combS[3][64];

    const int tid  = threadIdx.x;
    const int lane = tid & 63;
    const int wave = tid >> 6;
    const int l15 = lane & 15, l4 = lane >> 4;
    const int lane8 = lane * 8;
    const int row0 = blockIdx.x * RB;
    const int split = blockIdx.y;
    const int cb = (split * 4 + wave) * CPW;     // this wave's column base

    // A fragments straight from global (rows row0..row0+63), persistent
    short8 af[4][4];                             // [ks][fm]
#pragma unroll
    for (int fm = 0; fm < 4; ++fm)
#pragma unroll
        for (int ks = 0; ks < 4; ++ks)
            af[ks][fm] = *(const short8*)&F2[(size_t)((((row0 >> 4) + fm) * 4 + ks) * 512 + lane8)];

    float Sl[16];
#pragma unroll
    for (int x = 0; x < 16; ++x) Sl[x] = 0.f;

    // 3-buffer rotation, 2-deep prefetch (all names compile-time indexed)
    short8 b0[4], b1[4], b2[4];
    float r00, r01, r02;
    loadB(F2, cb, lane8, b0);       r00 = rcp0[cb + l15];
    loadB(F2, cb + 16, lane8, b1);  r01 = rcp0[cb + 16 + l15];

#pragma unroll 1
    for (int tt = 0; tt < NT; tt += 3) {
        {
            if (tt + 2 < NT) { int j = cb + (tt + 2) * 16; loadB(F2, j, lane8, b2); r02 = rcp0[j + l15]; }
            f32x4 acc[4];
            mfma16(af, b0, acc);
            epi16(acc, r00, Sl);
        }
        {
            if (tt + 3 < NT) { int j = cb + (tt + 3) * 16; loadB(F2, j, lane8, b0); r00 = rcp0[j + l15]; }
            f32x4 acc[4];
            mfma16(af, b1, acc);
            epi16(acc, r01, Sl);
        }
        {
            if (tt + 4 < NT) { int j = cb + (tt + 4) * 16; loadB(F2, j, lane8, b1); r01 = rcp0[j + l15]; }
            f32x4 acc[4];
            mfma16(af, b2, acc);
            epi16(acc, r02, Sl);
        }
    }

    // 16-lane column reduce (tree), then cross-wave combine via tiny LDS
#pragma unroll
    for (int idx = 0; idx < 16; ++idx) {
        float S = Sl[idx];
#pragma unroll
        for (int off = 1; off < 16; off <<= 1) S += __shfl_xor(S, off, 64);
        Sl[idx] = S;
        if (wave > 0 && l15 == 0) {
            int rl = (idx >> 2) * 16 + l4 * 4 + (idx & 3);
            combS[wave - 1][rl] = S;
        }
    }
    __syncthreads();
    if (wave == 0 && l15 == 0) {
#pragma unroll
        for (int idx = 0; idx < 16; ++idx) {
            int rl = (idx >> 2) * 16 + l4 * 4 + (idx & 3);
            S_part[split * BB + row0 + rl] = Sl[idx] + combS[0][rl] + combS[1][rl] + combS[2][rl];
        }
    }
}

// one wave per row: sparse mask correction + P + final lp, block partial sum
__global__ __launch_bounds__(256) void corr_kernel(
    const unsigned short* __restrict__ F2, const int* __restrict__ tgt,
    const int* __restrict__ cls, const int* __restrict__ off,
    const int* __restrict__ list, const float* __restrict__ rcp0,
    const float* __restrict__ rcpd, const float* __restrict__ S_part,
    float* __restrict__ bsum)
{
    __shared__ float wred[4];
    const int wave = threadIdx.x >> 6, lane = threadIdx.x & 63;
    const int i = blockIdx.x * 4 + wave;
    const int c = tgt[i];
    const int n = cls[c];                         // = npos (>=1: row i itself)
    const int o = off[c];
    const int k0 = lane * 2;
    const float fa = f2elem(F2, i, k0), fb = f2elem(F2, i, k0 + 1);

    float CorrS = 0.f, P = 0.f;
    for (int idx = 0; idx <= n; ++idx) {          // n batch members + 1 center
        int j = list[o + idx];
        float d = fa * f2elem(F2, j, k0) + fb * f2elem(F2, j, k0 + 1);
#pragma unroll
        for (int s = 1; s < 64; s <<= 1) d += __shfl_xor(d, s, 64);
        float e = fexp2(fmaf(d, K2F, -K2F));
        if (j == i) CorrS -= e * rcp0[i];         // remove self from S0
        else        { CorrS += e * rcpd[j]; P += d; }
    }
    float S = CorrS;
#pragma unroll
    for (int s = 0; s < NSPLIT; ++s) S += S_part[s * BB + i];
    float lp = fmaf(K2F, P / (float)n, -K2F) - flog2(S);   // log2 units

    if (lane == 0) wred[wave] = lp;
    __syncthreads();
    if (threadIdx.x == 0) bsum[blockIdx.x] = wred[0] + wred[1] + wred[2] + wred[3];
}

__global__ void out_kernel(const float* __restrict__ bsum, float* __restrict__ out) {
    const int tid = threadIdx.x;                  // 1024 threads
    float v = bsum[tid] + bsum[tid + 1024];
#pragma unroll
    for (int off = 1; off < 64; off <<= 1) v += __shfl_xor(v, off, 64);
    __shared__ float wsum[16];
    if ((tid & 63) == 0) wsum[tid >> 6] = v;
    __syncthreads();
    if (tid == 0) {
        float t = 0.f;
#pragma unroll
        for (int w = 0; w < 16; ++w) t += wsum[w];
        out[0] = -0.6931471805599453f * (t / (float)BB);   // ln2 * mean, negated
    }
}

extern "C" void kernel_launch(void* const* d_in, const int* in_sizes, int n_in,
                              void* d_out, int out_size, void* d_ws, size_t ws_size,
                              hipStream_t stream) {
    const float* ctrs  = (const float*)d_in[0];   // centers1 [1000,128]
    const float* feats = (const float*)d_in[1];   // features [8192,128]
    const int*   tgt   = (const int*)d_in[2];     // targets  [8192] int32
    float* out = (float*)d_out;
    float* ws  = (float*)d_ws;

    float* bsum = ws + WS_BSUM;
    int*   cls  = (int*)(ws + WS_CLS);
    int*   off  = (int*)(ws + WS_OFF);
    int*   list = (int*)(ws + WS_LIST);
    float* rcp0 = ws + WS_RCP0;
    float* rcpd = ws + WS_RCPD;
    float* Sp   = ws + WS_SPART;
    unsigned short* F2 = (unsigned short*)(ws + WS_F2);

    prep_kernel<<<dim3(145), dim3(1024), 0, stream>>>(feats, ctrs, tgt, F2, cls, off, list, rcp0, rcpd);
    main_kernel<<<dim3(BB / RB, NSPLIT), dim3(256), 0, stream>>>(F2, rcp0, Sp);
    corr_kernel<<<dim3(BB / 4), dim3(256), 0, stream>>>(F2, tgt, cls, off, list, rcp0, rcpd, Sp, bsum);
    out_kernel<<<dim3(1), dim3(1024), 0, stream>>>(bsum, out);
}

// Round 11
// 73.949 us; speedup vs baseline: 1.6996x; 1.1183x over previous
//
#include <hip/hip_runtime.h>
#include <math.h>

typedef __attribute__((ext_vector_type(8))) short short8;
typedef __attribute__((ext_vector_type(4))) float f32x4;

#define BB 8192      // batch
#define CC 1000      // classes
#define NN 9192      // B + C real columns
#define NPAD 9216    // padded
#define DD 128       // feature dim
#define RB 64        // rows per block
#define NSPLIT 4     // column splits (blockIdx.y) -> grid 512 = 2 blocks/CU exactly
#define CPW 576      // columns per wave = 9216/(NSPLIT*4)
#define NT 36        // 16-col chunks per wave (divisible by 3 for 3-buffer rotation)
#define K2F 14.426950408889634f   // (1/T) * log2(e)

// ---- workspace layout (float offsets) ----
#define WS_BSUM  0        // [2048] per-block lp sums (corr)
#define WS_CLS   2048     // [1024] int batch histogram
#define WS_OFF   3072     // [1024] int CSR offsets
#define WS_LIST  4096     // [9216] int CSR column lists
#define WS_RCP0  13312    // [9216] 1/cnt
#define WS_RCPD  22528    // [9216] 1/(cnt-1) - 1/cnt
#define WS_SPART 32768    // [4*8192]
#define WS_F2    98304    // fragment-major bf16 [9216*128]

static __device__ __forceinline__ unsigned short f2bf(float x) {
    unsigned int b = __float_as_uint(x);
    unsigned int r = (b + 0x7FFFu + ((b >> 16) & 1u)) >> 16;   // RNE
    return (unsigned short)r;
}
static __device__ __forceinline__ float fexp2(float x) {
    float r; asm("v_exp_f32 %0, %1" : "=v"(r) : "v"(x)); return r;
}
static __device__ __forceinline__ float flog2(float x) {
    float r; asm("v_log_f32 %0, %1" : "=v"(r) : "v"(x)); return r;
}
// element (row j, dim k) of fragment-major F2
static __device__ __forceinline__ float f2elem(const unsigned short* __restrict__ F2,
                                               int j, int k) {
    int u = ((j >> 4) * 4 + (k >> 5)) * 64 + ((k >> 3) & 3) * 16 + (j & 15);
    return __uint_as_float((unsigned int)F2[u * 8 + (k & 7)] << 16);
}

// ---- fused prep: blocks 0..143 convert fp32 -> fragment-major bf16;
//      block 144 builds hist + rcp tables + CSR fully in LDS (fill+sort) ----
__global__ __launch_bounds__(1024) void prep_kernel(
    const float* __restrict__ feats, const float* __restrict__ ctrs,
    const int* __restrict__ tgt, unsigned short* __restrict__ F2,
    int* __restrict__ cls, int* __restrict__ off, int* __restrict__ list,
    float* __restrict__ rcp0, float* __restrict__ rcpd)
{
    const int tid = threadIdx.x;
    if (blockIdx.x < 144) {
        // cvt: one short8-unit per thread.  F2 fragment-major: 16B unit
        // u = (j16*4 + ks)*64 + l4*16 + l15 holds (col j=j16*16+l15, k=ks*32+l4*8..+8)
        int u = blockIdx.x * 1024 + tid;          // < 147456 = NPAD*16
        int j = u >> 4, quad = u & 15;
        int k0 = quad * 8;
        float4 v0 = {0.f,0.f,0.f,0.f}, v1 = {0.f,0.f,0.f,0.f};
        if (j < BB) {
            v0 = *(const float4*)&feats[(size_t)j * DD + k0];
            v1 = *(const float4*)&feats[(size_t)j * DD + k0 + 4];
        } else if (j < NN) {
            v0 = *(const float4*)&ctrs[(size_t)(j - BB) * DD + k0];
            v1 = *(const float4*)&ctrs[(size_t)(j - BB) * DD + k0 + 4];
        }
        short8 o;
        o[0]=f2bf(v0.x); o[1]=f2bf(v0.y); o[2]=f2bf(v0.z); o[3]=f2bf(v0.w);
        o[4]=f2bf(v1.x); o[5]=f2bf(v1.y); o[6]=f2bf(v1.z); o[7]=f2bf(v1.w);
        size_t offb = (size_t)((((j >> 4) * 4 + (quad >> 2)) * 64 + (quad & 3) * 16 + (j & 15)) * 8);
        *(short8*)&F2[offb] = o;
        return;
    }

    // ---- setup block (runs concurrently with the cvt blocks) ----
    __shared__ int h[1024];
    __shared__ int s[1024];
    __shared__ int cur[1024];
    __shared__ int llds[NPAD];    // CSR list staged in LDS (36 KB)

    h[tid] = 0;
    __syncthreads();
    for (int i = tid; i < BB; i += 1024) atomicAdd(&h[tgt[i]], 1);
    __syncthreads();

    const int cnt_b = h[tid];            // batch members of class tid
    cls[tid] = cnt_b;

    // per-column weights
    for (int j = tid; j < NPAD; j += 1024) {
        if (j < NN) {
            int c = (j < BB) ? tgt[j] : (j - BB);
            int cnt = h[c] + 1;          // +1: the class center itself
            float a = 1.0f / (float)cnt;
            rcp0[j] = a;
            rcpd[j] = ((cnt > 1) ? 1.0f / (float)(cnt - 1) : 0.0f) - a;
        } else { rcp0[j] = 0.0f; rcpd[j] = 0.0f; }
    }

    // exclusive scan of segment lengths (members + center)
    int v = (tid < CC) ? cnt_b + 1 : 0;
    s[tid] = v;
    __syncthreads();
    for (int d = 1; d < 1024; d <<= 1) {
        int t = (tid >= d) ? s[tid - d] : 0;
        __syncthreads();
        s[tid] += t;
        __syncthreads();
    }
    const int o = s[tid] - v;
    if (tid < CC) { off[tid] = o; cur[tid] = o; }
    __syncthreads();

    // fill CSR lists in LDS (LDS atomic cursors)
    for (int j = tid; j < NN; j += 1024) {
        int c = (j < BB) ? tgt[j] : (j - BB);
        int r = atomicAdd(&cur[c], 1);
        llds[r] = j;
    }
    __syncthreads();

    // deterministic order within each segment (insertion sort in LDS)
    if (tid < CC) {
        int n = cnt_b + 1;
        for (int a = 1; a < n; ++a) {
            int key = llds[o + a]; int b = a - 1;
            while (b >= 0 && llds[o + b] > key) { llds[o + b + 1] = llds[o + b]; --b; }
            llds[o + b + 1] = key;
        }
    }
    __syncthreads();

    // coalesced write-out
    for (int j = tid; j < NN; j += 1024) list[j] = llds[j];
}

// one 16-col x 32-k fragment group (4 x 1KB coalesced loads)
static __device__ __forceinline__ void loadB(const unsigned short* __restrict__ F2,
                                             int j0, int lane8, short8 (&buf)[4]) {
#pragma unroll
    for (int ks = 0; ks < 4; ++ks)
        buf[ks] = *(const short8*)&F2[(size_t)(((j0 >> 4) * 4 + ks) * 512 + lane8)];
}

// 16 MFMAs: 64 rows x 16 cols x full K=128
static __device__ __forceinline__ void mfma16(const short8 (&af)[4][4], const short8 (&b)[4],
                                              f32x4 (&acc)[4]) {
    const f32x4 z4 = {0.f, 0.f, 0.f, 0.f};
#pragma unroll
    for (int fm = 0; fm < 4; ++fm)
        acc[fm] = __builtin_amdgcn_mfma_f32_16x16x32_bf16(af[0][fm], b[0], z4, 0, 0, 0);
#pragma unroll
    for (int ks = 1; ks < 4; ++ks)
#pragma unroll
        for (int fm = 0; fm < 4; ++fm)
            acc[fm] = __builtin_amdgcn_mfma_f32_16x16x32_bf16(
                af[ks][fm], b[ks], acc[fm], 0, 0, 0);
}

// 3 VALU per element: fma -> v_exp -> fmac  (no masks, no metadata)
static __device__ __forceinline__ void epi16(const f32x4 (&acc)[4], float r0, float (&Sl)[16]) {
#pragma unroll
    for (int fm = 0; fm < 4; ++fm)
#pragma unroll
        for (int q = 0; q < 4; ++q) {
            float l2 = fmaf(acc[fm][q], K2F, -K2F);
            Sl[fm * 4 + q] = fmaf(fexp2(l2), r0, Sl[fm * 4 + q]);
        }
}

__global__ __launch_bounds__(256, 2) void main_kernel(
    const unsigned short* __restrict__ F2, const float* __restrict__ rcp0,
    float* __restrict__ S_part)
{
    __shared__ float combS[3][64];

    const int tid  = threadIdx.x;
    const int lane = tid & 63;
    const int wave = tid >> 6;
    const int l15 = lane & 15, l4 = lane >> 4;
    const int lane8 = lane * 8;
    const int row0 = blockIdx.x * RB;
    const int split = blockIdx.y;
    const int cb = (split * 4 + wave) * CPW;     // this wave's column base

    // A fragments straight from global (rows row0..row0+63), persistent
    short8 af[4][4];                             // [ks][fm]
#pragma unroll
    for (int fm = 0; fm < 4; ++fm)
#pragma unroll
        for (int ks = 0; ks < 4; ++ks)
            af[ks][fm] = *(const short8*)&F2[(size_t)((((row0 >> 4) + fm) * 4 + ks) * 512 + lane8)];

    float Sl[16];
#pragma unroll
    for (int x = 0; x < 16; ++x) Sl[x] = 0.f;

    // 3-buffer rotation, 2-deep prefetch (all names compile-time indexed)
    short8 b0[4], b1[4], b2[4];
    float r00, r01, r02;
    loadB(F2, cb, lane8, b0);       r00 = rcp0[cb + l15];
    loadB(F2, cb + 16, lane8, b1);  r01 = rcp0[cb + 16 + l15];

#pragma unroll 1
    for (int tt = 0; tt < NT; tt += 3) {
        {
            if (tt + 2 < NT) { int j = cb + (tt + 2) * 16; loadB(F2, j, lane8, b2); r02 = rcp0[j + l15]; }
            f32x4 acc[4];
            mfma16(af, b0, acc);
            epi16(acc, r00, Sl);
        }
        {
            if (tt + 3 < NT) { int j = cb + (tt + 3) * 16; loadB(F2, j, lane8, b0); r00 = rcp0[j + l15]; }
            f32x4 acc[4];
            mfma16(af, b1, acc);
            epi16(acc, r01, Sl);
        }
        {
            if (tt + 4 < NT) { int j = cb + (tt + 4) * 16; loadB(F2, j, lane8, b1); r01 = rcp0[j + l15]; }
            f32x4 acc[4];
            mfma16(af, b2, acc);
            epi16(acc, r02, Sl);
        }
    }

    // 16-lane column reduce (tree), then cross-wave combine via tiny LDS
#pragma unroll
    for (int idx = 0; idx < 16; ++idx) {
        float S = Sl[idx];
#pragma unroll
        for (int off = 1; off < 16; off <<= 1) S += __shfl_xor(S, off, 64);
        Sl[idx] = S;
        if (wave > 0 && l15 == 0) {
            int rl = (idx >> 2) * 16 + l4 * 4 + (idx & 3);
            combS[wave - 1][rl] = S;
        }
    }
    __syncthreads();
    if (wave == 0 && l15 == 0) {
#pragma unroll
        for (int idx = 0; idx < 16; ++idx) {
            int rl = (idx >> 2) * 16 + l4 * 4 + (idx & 3);
            S_part[split * BB + row0 + rl] = Sl[idx] + combS[0][rl] + combS[1][rl] + combS[2][rl];
        }
    }
}

// one wave per row: sparse mask correction + P + final lp, block partial sum
__global__ __launch_bounds__(256) void corr_kernel(
    const unsigned short* __restrict__ F2, const int* __restrict__ tgt,
    const int* __restrict__ cls, const int* __restrict__ off,
    const int* __restrict__ list, const float* __restrict__ rcp0,
    const float* __restrict__ rcpd, const float* __restrict__ S_part,
    float* __restrict__ bsum)
{
    __shared__ float wred[4];
    const int wave = threadIdx.x >> 6, lane = threadIdx.x & 63;
    const int i = blockIdx.x * 4 + wave;
    const int c = tgt[i];
    const int n = cls[c];                         // = npos (>=1: row i itself)
    const int o = off[c];
    const int k0 = lane * 2;
    const float fa = f2elem(F2, i, k0), fb = f2elem(F2, i, k0 + 1);

    float CorrS = 0.f, P = 0.f;
    for (int idx = 0; idx <= n; ++idx) {          // n batch members + 1 center
        int j = list[o + idx];
        float d = fa * f2elem(F2, j, k0) + fb * f2elem(F2, j, k0 + 1);
#pragma unroll
        for (int s = 1; s < 64; s <<= 1) d += __shfl_xor(d, s, 64);
        float e = fexp2(fmaf(d, K2F, -K2F));
        if (j == i) CorrS -= e * rcp0[i];         // remove self from S0
        else        { CorrS += e * rcpd[j]; P += d; }
    }
    float S = CorrS;
#pragma unroll
    for (int s = 0; s < NSPLIT; ++s) S += S_part[s * BB + i];
    float lp = fmaf(K2F, P / (float)n, -K2F) - flog2(S);   // log2 units

    if (lane == 0) wred[wave] = lp;
    __syncthreads();
    if (threadIdx.x == 0) bsum[blockIdx.x] = wred[0] + wred[1] + wred[2] + wred[3];
}

__global__ void out_kernel(const float* __restrict__ bsum, float* __restrict__ out) {
    const int tid = threadIdx.x;                  // 1024 threads
    float v = bsum[tid] + bsum[tid + 1024];
#pragma unroll
    for (int off = 1; off < 64; off <<= 1) v += __shfl_xor(v, off, 64);
    __shared__ float wsum[16];
    if ((tid & 63) == 0) wsum[tid >> 6] = v;
    __syncthreads();
    if (tid == 0) {
        float t = 0.f;
#pragma unroll
        for (int w = 0; w < 16; ++w) t += wsum[w];
        out[0] = -0.6931471805599453f * (t / (float)BB);   // ln2 * mean, negated
    }
}

extern "C" void kernel_launch(void* const* d_in, const int* in_sizes, int n_in,
                              void* d_out, int out_size, void* d_ws, size_t ws_size,
                              hipStream_t stream) {
    const float* ctrs  = (const float*)d_in[0];   // centers1 [1000,128]
    const float* feats = (const float*)d_in[1];   // features [8192,128]
    const int*   tgt   = (const int*)d_in[2];     // targets  [8192] int32
    float* out = (float*)d_out;
    float* ws  = (float*)d_ws;

    float* bsum = ws + WS_BSUM;
    int*   cls  = (int*)(ws + WS_CLS);
    int*   off  = (int*)(ws + WS_OFF);
    int*   list = (int*)(ws + WS_LIST);
    float* rcp0 = ws + WS_RCP0;
    float* rcpd = ws + WS_RCPD;
    float* Sp   = ws + WS_SPART;
    unsigned short* F2 = (unsigned short*)(ws + WS_F2);

    prep_kernel<<<dim3(145), dim3(1024), 0, stream>>>(feats, ctrs, tgt, F2, cls, off, list, rcp0, rcpd);
    main_kernel<<<dim3(BB / RB, NSPLIT), dim3(256), 0, stream>>>(F2, rcp0, Sp);
    corr_kernel<<<dim3(BB / 4), dim3(256), 0, stream>>>(F2, tgt, cls, off, list, rcp0, rcpd, Sp, bsum);
    out_kernel<<<dim3(1), dim3(1024), 0, stream>>>(bsum, out);
}